// Round 7
// baseline (184.825 us; speedup 1.0000x reference)
//
#include <hip/hip_runtime.h>

#define B_  8
#define C_  64
#define H_  128
#define W_  128
#define HW_ (H_*W_)
#define NP_ ((size_t)B_*HW_)   // total pixels = 131072

typedef __attribute__((ext_vector_type(4)))  float f32x4;
typedef __attribute__((ext_vector_type(16))) float f32x16;
typedef __attribute__((ext_vector_type(8)))  short short8;

static __device__ __forceinline__ unsigned short f2bf(float f) {
  unsigned int u = __float_as_uint(f);
  u += 0x7fff + ((u >> 16) & 1);   // round-to-nearest-even
  return (unsigned short)(u >> 16);
}
static __device__ __forceinline__ float bf2f(unsigned short u) {
  return __uint_as_float((unsigned int)u << 16);
}

// ---------------- kernel 0: weight prep ----------------
__global__ void k0_prep(const float* __restrict__ w, const float* __restrict__ wred,
                        const float* __restrict__ g3, const float* __restrict__ b3,
                        const float* __restrict__ m3, const float* __restrict__ v3,
                        unsigned short* __restrict__ afrag,
                        unsigned short* __restrict__ afrag_red,
                        float* __restrict__ s3, float* __restrict__ sh3) {
  int idx = blockIdx.x * 256 + threadIdx.x;
  if (idx < 36864) {
    int j    = idx & 7;
    int lane = (idx >> 3) & 63;
    int fs   = idx >> 9;          // 0..71
    int ks16 = fs & 3;
    int kk   = (fs >> 2) % 9;
    int mh   = fs / 36;
    int oc = mh * 32 + (lane & 31);
    int ic = ks16 * 16 + (lane >> 5) * 8 + j;
    afrag[idx] = f2bf(w[(oc * 64 + ic) * 9 + kk]);
  } else if (idx < 38912) {
    int i2 = idx - 36864;         // 0..2047
    int j    = i2 & 7;
    int lane = (i2 >> 3) & 63;
    int ks   = i2 >> 9;           // 0..3
    int m  = lane & 31;
    int ic = ks * 16 + (lane >> 5) * 8 + j;
    afrag_red[i2] = (m < 16) ? f2bf(wred[m * 64 + ic]) : (unsigned short)0;
  } else if (idx < 38976) {
    int c = idx - 38912;
    float s = g3[c] * rsqrtf(v3[c] + 1e-5f);
    s3[c]  = s;
    sh3[c] = b3[c] - m3[c] * s;
  }
}

// ---------------- kernel 1: fused kernel-gen + involution ----------------
// 256 threads = 4 waves; output tile 4 rows x 32 cols; wave = 1 row, 2 lanes
// per pixel (h = lane>>5 owns channel half). Target tile 6 rows x 36 cols x
// 64ch staged to LDS bf16 via ROW-STREAMING float4 loads + u16 transpose
// writes (2 lanes/bank = free). LDS cell layout [cell][chunk^(cell&7)].
__global__ __launch_bounds__(256, 4) void k1_fused(
    const float* __restrict__ guide, const float* __restrict__ target,
    const unsigned short* __restrict__ afrag_red,
    const float* __restrict__ bn1g, const float* __restrict__ bn1b,
    const float* __restrict__ bn1m, const float* __restrict__ bn1v,
    const float* __restrict__ w_span, const float* __restrict__ b_span,
    unsigned short* __restrict__ inv) {
  __shared__ __align__(16) unsigned short t16[216 * 64];   // 6*36 cells *128B = 27648 B
  __shared__ f32x4 s_wspan[18][4];
  __shared__ f32x4 s_s1v[4], s_sh1v[4];
  __shared__ float s_bsp[18];
  int t = threadIdx.x;
  for (int i = t; i < 288; i += 256) {
    int j = i >> 4, r = i & 15;
    ((float*)&s_wspan[j][0])[r] = w_span[i];
  }
  if (t < 16) {
    float s = bn1g[t] * rsqrtf(bn1v[t] + 1e-5f);
    ((float*)s_s1v)[t]  = s;
    ((float*)s_sh1v)[t] = bn1b[t] - bn1m[t] * s;
  }
  if (t < 18) s_bsp[t] = b_span[t];

  int b  = blockIdx.z;
  int r0 = blockIdx.y * 4;          // output rows r0..r0+3
  int w0 = blockIdx.x * 32;         // output cols w0..w0+31
  const float* tb = target + (size_t)b * C_ * HW_;

  // stage target rows r0-1..r0+4, cols w0-2..w0+33 -> LDS bf16.
  // i = tr*64 + c: one (channel, tile-row) pair; 10 aligned float4 along W.
  for (int i = t; i < 384; i += 256) {
    int tr = i >> 6, c = i & 63;
    int gr = r0 - 1 + tr;
    bool rv = (unsigned)gr < (unsigned)H_;
    const float* src = tb + (size_t)c * HW_ + gr * W_;
    #pragma unroll
    for (int j = 0; j < 10; ++j) {
      int g0 = w0 - 4 + 4 * j;
      f32x4 v = {0.f, 0.f, 0.f, 0.f};
      if (rv && g0 >= 0 && g0 <= W_ - 4) v = *(const f32x4*)(src + g0);
      #pragma unroll
      for (int e = 0; e < 4; ++e) {
        int lc = 4 * j + e - 2;
        if (lc >= 0 && lc < 36) {
          int cell = tr * 36 + lc;
          t16[cell * 64 + (((c >> 3) ^ (cell & 7)) * 8) + (c & 7)] = f2bf(v[e]);
        }
      }
    }
  }

  int wave = t >> 6, l = t & 63, h = l >> 5;
  short8 a_red[4];
  #pragma unroll
  for (int ks = 0; ks < 4; ++ks)
    a_red[ks] = *(const short8*)(afrag_red + ((size_t)(ks * 64 + l)) * 8);
  __syncthreads();

  int ty = wave, tx = l & 31;       // wave = one output row of 32 cols
  const float* gpx = guide + (size_t)b * C_ * HW_ + (r0 + ty) * W_ + (w0 + tx);
  int cellC = (ty + 1) * 36 + (tx + 2);

  // phase A: reduce conv via MFMA (guide loads coalesced: wave spans one row)
  f32x16 xa;
  #pragma unroll
  for (int i = 0; i < 16; ++i) xa[i] = 0.f;
  #pragma unroll
  for (int ks = 0; ks < 4; ++ks) {
    short8 tvv = *(const short8*)&t16[cellC * 64 + (((2 * ks + h) ^ (cellC & 7)) * 8)];
    int ch0 = ks * 16 + h * 8;
    short8 bf;
    #pragma unroll
    for (int j = 0; j < 8; ++j)
      bf[j] = (short)f2bf(gpx[(size_t)(ch0 + j) * HW_] + bf2f((unsigned short)tvv[j]));
    xa = __builtin_amdgcn_mfma_f32_32x32x16_bf16(a_red[ks], bf, xa, 0, 0, 0);
  }
  // BN1 + ReLU (valid C-rows: regs 0..7)
  f32x4 x0, x1;
  #pragma unroll
  for (int r = 0; r < 4; ++r) { x0[r] = xa[r]; x1[r] = xa[4 + r]; }
  {
    f32x4 sA = s_s1v[h], shA = s_sh1v[h], sB = s_s1v[2 + h], shB = s_sh1v[2 + h];
    #pragma unroll
    for (int r = 0; r < 4; ++r) {
      x0[r] = fmaxf(x0[r] * sA[r] + shA[r], 0.f);
      x1[r] = fmaxf(x1[r] * sB[r] + shB[r], 0.f);
    }
  }

  // phase B: span conv; partner-half exchange via shfl_xor(32)
  float kg[9];
  #pragma unroll
  for (int j9 = 0; j9 < 9; ++j9) {
    int jA = h * 9 + j9;
    int jB = (9 - 9 * h) + j9;
    f32x4 wA0 = s_wspan[jA][h], wA1 = s_wspan[jA][2 + h];
    f32x4 wB0 = s_wspan[jB][h], wB1 = s_wspan[jB][2 + h];
    float pa = 0.f, pb = 0.f;
    #pragma unroll
    for (int r = 0; r < 4; ++r) {
      pa += wA0[r] * x0[r] + wA1[r] * x1[r];
      pb += wB0[r] * x0[r] + wB1[r] * x1[r];
    }
    float recv = __shfl_xor(pb, 32, 64);
    kg[j9] = pa + recv + s_bsp[jA];
  }

  // phase C: involution for chunks c8 = 4h..4h+3
  size_t pix = ((size_t)b * H_ + (r0 + ty)) * W_ + (w0 + tx);
  #pragma unroll
  for (int i = 0; i < 4; ++i) {
    int c8 = h * 4 + i;
    float a8[8];
    #pragma unroll
    for (int ci = 0; ci < 8; ++ci) a8[ci] = 0.f;
    #pragma unroll
    for (int di = 0; di < 3; ++di) {
      #pragma unroll
      for (int dj = 0; dj < 3; ++dj) {
        int cell = (ty + di) * 36 + (tx + dj + 1);
        short8 tv = *(const short8*)&t16[cell * 64 + ((c8 ^ (cell & 7)) * 8)];
        float k = kg[di * 3 + dj];
        #pragma unroll
        for (int ci = 0; ci < 8; ++ci) a8[ci] += k * bf2f((unsigned short)tv[ci]);
      }
    }
    short8 pv;
    #pragma unroll
    for (int ci = 0; ci < 8; ++ci) pv[ci] = (short)f2bf(a8[ci]);
    *(short8*)(inv + ((size_t)c8 * NP_ + pix) * 8) = pv;
  }
}

// ---------------- kernel 2: 3x3 conv via mfma_32x32x16 + BN3 + ReLU ----------
__global__ __launch_bounds__(256, 4) void k2_conv(
    const unsigned short* __restrict__ inv, const unsigned short* __restrict__ afrag,
    const float* __restrict__ s3g, const float* __restrict__ sh3g,
    float* __restrict__ out) {
  __shared__ __align__(16) unsigned short tile[204 * 64];   // 26112 B
  int t = threadIdx.x;
  int b  = blockIdx.z;
  int h0 = blockIdx.y * 4;
  int w0 = blockIdx.x * 32;

  #pragma unroll
  for (int chunk = 0; chunk < 8; ++chunk) {
    if (t < 204) {
      int r = t / 34, col = t - r * 34;
      int hh = h0 + r - 1, ww = w0 + col - 1;
      short8 val = {0, 0, 0, 0, 0, 0, 0, 0};
      if ((unsigned)hh < (unsigned)H_ && (unsigned)ww < (unsigned)W_)
        val = *(const short8*)(inv + ((size_t)chunk * NP_ + ((size_t)b * H_ + hh) * W_ + ww) * 8);
      *(short8*)&tile[t * 64 + ((chunk ^ (col & 7)) * 8)] = val;
    }
  }

  int wave = t >> 6, lane = t & 63;
  int mh = wave & 1;
  int rp = (wave >> 1) * 2;
  __syncthreads();

  f32x16 acc0, acc1;
  #pragma unroll
  for (int i = 0; i < 16; ++i) { acc0[i] = 0.f; acc1[i] = 0.f; }

  for (int kk = 0; kk < 9; ++kk) {
    int di = kk / 3, dj = kk - di * 3;
    const unsigned short* ap = afrag + (((size_t)(mh * 9 + kk) * 4) * 64 + lane) * 8;
    short8 A0 = *(const short8*)(ap);
    short8 A1 = *(const short8*)(ap + 512);
    short8 A2 = *(const short8*)(ap + 1024);
    short8 A3 = *(const short8*)(ap + 1536);
    int col = (lane & 31) + dj;
    int swb = (lane >> 5);
    int cb0 = (rp + di) * 34 + col;
    #pragma unroll
    for (int ks = 0; ks < 4; ++ks) {
      int sw = ((ks * 2 + swb) ^ (col & 7)) * 8;
      short8 b0 = *(const short8*)&tile[cb0 * 64 + sw];
      short8 b1 = *(const short8*)&tile[(cb0 + 34) * 64 + sw];
      short8 Ak = (ks == 0) ? A0 : (ks == 1) ? A1 : (ks == 2) ? A2 : A3;
      acc0 = __builtin_amdgcn_mfma_f32_32x32x16_bf16(Ak, b0, acc0, 0, 0, 0);
      acc1 = __builtin_amdgcn_mfma_f32_32x32x16_bf16(Ak, b1, acc1, 0, 0, 0);
    }
  }

  int wcol = lane & 31;
  #pragma unroll
  for (int reg = 0; reg < 16; ++reg) {
    int oc = mh * 32 + (reg & 3) + 8 * (reg >> 2) + 4 * (lane >> 5);
    float s  = s3g[oc];
    float sh = sh3g[oc];
    float* op = out + ((size_t)b * C_ + oc) * HW_ + (h0 + rp) * W_ + w0 + wcol;
    op[0]  = fmaxf(acc0[reg] * s + sh, 0.f);
    op[W_] = fmaxf(acc1[reg] * s + sh, 0.f);
  }
}

extern "C" void kernel_launch(void* const* d_in, const int* in_sizes, int n_in,
                              void* d_out, int out_size, void* d_ws, size_t ws_size,
                              hipStream_t stream) {
  const float* guide    = (const float*)d_in[0];
  const float* target   = (const float*)d_in[1];
  const float* w_reduce = (const float*)d_in[2];
  const float* bn1g     = (const float*)d_in[3];
  const float* bn1b     = (const float*)d_in[4];
  const float* bn1m     = (const float*)d_in[5];
  const float* bn1v     = (const float*)d_in[6];
  const float* w_span   = (const float*)d_in[7];
  const float* b_span   = (const float*)d_in[8];
  const float* w_bconv  = (const float*)d_in[9];
  const float* bn3g     = (const float*)d_in[10];
  const float* bn3b     = (const float*)d_in[11];
  const float* bn3m     = (const float*)d_in[12];
  const float* bn3v     = (const float*)d_in[13];
  float* out = (float*)d_out;

  unsigned short* afrag     = (unsigned short*)d_ws;                      // 73728 B
  unsigned short* afrag_red = (unsigned short*)((char*)d_ws + 81920);     // 4096 B
  float* s3  = (float*)((char*)d_ws + 90112);
  float* sh3 = (float*)((char*)d_ws + 90368);
  unsigned short* inv = (unsigned short*)((char*)d_ws + (1 << 17));       // 16.8 MB

  hipLaunchKernelGGL(k0_prep, dim3(153), dim3(256), 0, stream,
                     w_bconv, w_reduce, bn3g, bn3b, bn3m, bn3v,
                     afrag, afrag_red, s3, sh3);
  hipLaunchKernelGGL(k1_fused, dim3(W_ / 32, H_ / 4, B_), dim3(256), 0, stream,
                     guide, target, afrag_red, bn1g, bn1b, bn1m, bn1v,
                     w_span, b_span, inv);
  hipLaunchKernelGGL(k2_conv, dim3(W_ / 32, H_ / 4, B_), dim3(256), 0, stream,
                     inv, afrag, s3, sh3, out);
}

// Round 8
// 167.414 us; speedup vs baseline: 1.1040x; 1.1040x over previous
//
#include <hip/hip_runtime.h>

#define B_  8
#define C_  64
#define H_  128
#define W_  128
#define HW_ (H_*W_)
#define NP_ ((size_t)B_*HW_)   // total pixels = 131072

typedef __attribute__((ext_vector_type(4)))  float f32x4;
typedef __attribute__((ext_vector_type(16))) float f32x16;
typedef __attribute__((ext_vector_type(8)))  short short8;

static __device__ __forceinline__ unsigned short f2bf(float f) {
  unsigned int u = __float_as_uint(f);
  u += 0x7fff + ((u >> 16) & 1);   // round-to-nearest-even
  return (unsigned short)(u >> 16);
}
static __device__ __forceinline__ float bf2f(unsigned short u) {
  return __uint_as_float((unsigned int)u << 16);
}

// ---------------- kernel 0: weight prep ----------------
__global__ void k0_prep(const float* __restrict__ w, const float* __restrict__ wred,
                        const float* __restrict__ g3, const float* __restrict__ b3,
                        const float* __restrict__ m3, const float* __restrict__ v3,
                        unsigned short* __restrict__ afrag,
                        unsigned short* __restrict__ afrag_red,
                        float* __restrict__ s3, float* __restrict__ sh3) {
  int idx = blockIdx.x * 256 + threadIdx.x;
  if (idx < 36864) {
    int j    = idx & 7;
    int lane = (idx >> 3) & 63;
    int fs   = idx >> 9;          // 0..71
    int ks16 = fs & 3;
    int kk   = (fs >> 2) % 9;
    int mh   = fs / 36;
    int oc = mh * 32 + (lane & 31);
    int ic = ks16 * 16 + (lane >> 5) * 8 + j;
    afrag[idx] = f2bf(w[(oc * 64 + ic) * 9 + kk]);
  } else if (idx < 38912) {
    int i2 = idx - 36864;         // 0..2047
    int j    = i2 & 7;
    int lane = (i2 >> 3) & 63;
    int ks   = i2 >> 9;           // 0..3
    int m  = lane & 31;
    int ic = ks * 16 + (lane >> 5) * 8 + j;
    afrag_red[i2] = (m < 16) ? f2bf(wred[m * 64 + ic]) : (unsigned short)0;
  } else if (idx < 38976) {
    int c = idx - 38912;
    float s = g3[c] * rsqrtf(v3[c] + 1e-5f);
    s3[c]  = s;
    sh3[c] = b3[c] - m3[c] * s;
  }
}

// ---------------- kernel 1: fused kernel-gen + involution ----------------
// (R6 version, measured <=41 us, passed) 512 threads = 8 waves; 16x16 pixel
// tile; 2 lanes per pixel (h = lane>>5 owns channel half / chunks 4h..4h+3 /
// kern group h). Kernel-gen via mfma_32x32x16 (w_reduce = A).
// Target tile (18x18 halo x 64ch) in LDS bf16 [cell][chunk^(cell&7)].
__global__ __launch_bounds__(512, 4) void k1_fused(
    const float* __restrict__ guide, const float* __restrict__ target,
    const unsigned short* __restrict__ afrag_red,
    const float* __restrict__ bn1g, const float* __restrict__ bn1b,
    const float* __restrict__ bn1m, const float* __restrict__ bn1v,
    const float* __restrict__ w_span, const float* __restrict__ b_span,
    unsigned short* __restrict__ inv) {
  __shared__ __align__(16) unsigned short t16[324 * 64];   // 41472 B
  __shared__ f32x4 s_wspan[18][4];                         // [j][quad]
  __shared__ f32x4 s_s1v[4], s_sh1v[4];
  __shared__ float s_bsp[18];
  int t = threadIdx.x;
  if (t < 288) {
    int j = t >> 4, r = t & 15;
    ((float*)&s_wspan[j][0])[r] = w_span[t];     // w_span[j*16+r]
  }
  if (t < 16) {
    float s = bn1g[t] * rsqrtf(bn1v[t] + 1e-5f);
    ((float*)s_s1v)[t]  = s;
    ((float*)s_sh1v)[t] = bn1b[t] - bn1m[t] * s;
  }
  if (t < 18) s_bsp[t] = b_span[t];

  int b  = blockIdx.z;
  int h0 = blockIdx.y * 16, w0 = blockIdx.x * 16;
  const float* tb = target + (size_t)b * C_ * HW_;

  // stage target tile -> LDS bf16 [cell][chunk ^ (cell&7)]
  for (int i = t; i < 2592; i += 512) {
    int c8 = i / 324, cell = i - c8 * 324;
    int r = cell / 18, col = cell - r * 18;
    int hh = h0 + r - 1, ww = w0 + col - 1;
    short8 val = {0, 0, 0, 0, 0, 0, 0, 0};
    if ((unsigned)hh < (unsigned)H_ && (unsigned)ww < (unsigned)W_) {
      const float* src = tb + (size_t)(c8 * 8) * HW_ + hh * W_ + ww;
      #pragma unroll
      for (int ci = 0; ci < 8; ++ci) val[ci] = (short)f2bf(src[(size_t)ci * HW_]);
    }
    *(short8*)&t16[cell * 64 + ((c8 ^ (cell & 7)) * 8)] = val;
  }

  int wave = t >> 6, l = t & 63, h = l >> 5;
  short8 a_red[4];
  #pragma unroll
  for (int ks = 0; ks < 4; ++ks)
    a_red[ks] = *(const short8*)(afrag_red + ((size_t)(ks * 64 + l)) * 8);
  __syncthreads();

  int p   = wave * 32 + (l & 31);          // this lane's pixel (0..255)
  int tyP = p >> 4, txP = p & 15;
  const float* gpx = guide + (size_t)b * C_ * HW_ + (h0 + tyP) * W_ + (w0 + txP);
  int cellC = (tyP + 1) * 18 + (txP + 1);

  // phase A: reduce conv via MFMA
  f32x16 xa;
  #pragma unroll
  for (int i = 0; i < 16; ++i) xa[i] = 0.f;
  #pragma unroll
  for (int ks = 0; ks < 4; ++ks) {
    short8 tvv = *(const short8*)&t16[cellC * 64 + (((2 * ks + h) ^ (cellC & 7)) * 8)];
    int ch0 = ks * 16 + h * 8;
    short8 bf;
    #pragma unroll
    for (int j = 0; j < 8; ++j)
      bf[j] = (short)f2bf(gpx[(size_t)(ch0 + j) * HW_] + bf2f((unsigned short)tvv[j]));
    xa = __builtin_amdgcn_mfma_f32_32x32x16_bf16(a_red[ks], bf, xa, 0, 0, 0);
  }
  // BN1 + ReLU
  f32x4 x0, x1;
  #pragma unroll
  for (int r = 0; r < 4; ++r) { x0[r] = xa[r]; x1[r] = xa[4 + r]; }
  {
    f32x4 sA = s_s1v[h], shA = s_sh1v[h], sB = s_s1v[2 + h], shB = s_sh1v[2 + h];
    #pragma unroll
    for (int r = 0; r < 4; ++r) {
      x0[r] = fmaxf(x0[r] * sA[r] + shA[r], 0.f);
      x1[r] = fmaxf(x1[r] * sB[r] + shB[r], 0.f);
    }
  }

  // phase B: span conv; partner-half exchange via shfl_xor(32)
  float kg[9];
  #pragma unroll
  for (int j9 = 0; j9 < 9; ++j9) {
    int jA = h * 9 + j9;
    int jB = (9 - 9 * h) + j9;
    f32x4 wA0 = s_wspan[jA][h], wA1 = s_wspan[jA][2 + h];
    f32x4 wB0 = s_wspan[jB][h], wB1 = s_wspan[jB][2 + h];
    float pa = 0.f, pb = 0.f;
    #pragma unroll
    for (int r = 0; r < 4; ++r) {
      pa += wA0[r] * x0[r] + wA1[r] * x1[r];
      pb += wB0[r] * x0[r] + wB1[r] * x1[r];
    }
    float recv = __shfl_xor(pb, 32, 64);
    kg[j9] = pa + recv + s_bsp[jA];
  }

  // phase C: involution for chunks c8 = 4h..4h+3
  size_t pix = ((size_t)b * H_ + (h0 + tyP)) * W_ + (w0 + txP);
  #pragma unroll
  for (int i = 0; i < 4; ++i) {
    int c8 = h * 4 + i;
    float a8[8];
    #pragma unroll
    for (int ci = 0; ci < 8; ++ci) a8[ci] = 0.f;
    #pragma unroll
    for (int di = 0; di < 3; ++di) {
      #pragma unroll
      for (int dj = 0; dj < 3; ++dj) {
        int cell = (tyP + di) * 18 + (txP + dj);
        short8 tv = *(const short8*)&t16[cell * 64 + ((c8 ^ (cell & 7)) * 8)];
        float k = kg[di * 3 + dj];
        #pragma unroll
        for (int ci = 0; ci < 8; ++ci) a8[ci] += k * bf2f((unsigned short)tv[ci]);
      }
    }
    short8 pv;
    #pragma unroll
    for (int ci = 0; ci < 8; ++ci) pv[ci] = (short)f2bf(a8[ci]);
    *(short8*)(inv + ((size_t)c8 * NP_ + pix) * 8) = pv;
  }
}

// ---------------- kernel 2: 3x3 conv, NO LDS — direct coalesced inv loads ---
// block 256 = 4 waves; tile = 64 oc x 4 rows x 32 w. wave: mh = wave&1,
// rows rp..rp+1. B-frag = one short8/lane straight from chunk-major inv
// (lanes 0-31: 512 B contiguous; lanes 32-63: adjacent chunk). Fully
// unrolled 9x4 -> 72 independent loads pipeline; borders via clamped
// address + select-zero.
__global__ __launch_bounds__(256, 4) void k2_conv(
    const unsigned short* __restrict__ inv, const unsigned short* __restrict__ afrag,
    const float* __restrict__ s3g, const float* __restrict__ sh3g,
    float* __restrict__ out) {
  int t = threadIdx.x;
  int wave = t >> 6, lane = t & 63;
  int mh = wave & 1;
  int rp = (wave >> 1) * 2;
  int b  = blockIdx.z;
  int h0 = blockIdx.y * 4;
  int w0 = blockIdx.x * 32;
  int tx = lane & 31, hb = lane >> 5;

  f32x16 acc0, acc1;
  #pragma unroll
  for (int i = 0; i < 16; ++i) { acc0[i] = 0.f; acc1[i] = 0.f; }

  const size_t bbase = (size_t)b * H_;
  const short8 z = {0, 0, 0, 0, 0, 0, 0, 0};

  #pragma unroll
  for (int kk = 0; kk < 9; ++kk) {
    const int di = kk / 3, dj = kk - di * 3;
    const unsigned short* ap = afrag + (((size_t)(mh * 9 + kk) * 4) * 64 + lane) * 8;
    int wj = w0 + tx + dj - 1;
    bool cok = (unsigned)wj < (unsigned)W_;
    int wc = min(max(wj, 0), W_ - 1);
    int hr0 = h0 + rp + di - 1;
    int hr1 = hr0 + 1;
    bool r0ok = cok && ((unsigned)hr0 < (unsigned)H_);
    bool r1ok = cok && ((unsigned)hr1 < (unsigned)H_);
    int hc0 = min(max(hr0, 0), H_ - 1);
    int hc1 = min(max(hr1, 0), H_ - 1);
    size_t p0 = (bbase + hc0) * W_ + wc;
    size_t p1 = (bbase + hc1) * W_ + wc;
    #pragma unroll
    for (int ks = 0; ks < 4; ++ks) {
      int c8 = ks * 2 + hb;
      short8 A  = *(const short8*)(ap + (size_t)ks * 512);
      short8 v0 = *(const short8*)(inv + ((size_t)c8 * NP_ + p0) * 8);
      short8 v1 = *(const short8*)(inv + ((size_t)c8 * NP_ + p1) * 8);
      short8 b0 = r0ok ? v0 : z;
      short8 b1 = r1ok ? v1 : z;
      acc0 = __builtin_amdgcn_mfma_f32_32x32x16_bf16(A, b0, acc0, 0, 0, 0);
      acc1 = __builtin_amdgcn_mfma_f32_32x32x16_bf16(A, b1, acc1, 0, 0, 0);
    }
  }

  // epilogue: BN3 + ReLU, NCHW f32
  int wcol = lane & 31;
  #pragma unroll
  for (int reg = 0; reg < 16; ++reg) {
    int oc = mh * 32 + (reg & 3) + 8 * (reg >> 2) + 4 * (lane >> 5);
    float s  = s3g[oc];
    float sh = sh3g[oc];
    float* op = out + ((size_t)b * C_ + oc) * HW_ + (h0 + rp) * W_ + w0 + wcol;
    op[0]  = fmaxf(acc0[reg] * s + sh, 0.f);
    op[W_] = fmaxf(acc1[reg] * s + sh, 0.f);
  }
}

extern "C" void kernel_launch(void* const* d_in, const int* in_sizes, int n_in,
                              void* d_out, int out_size, void* d_ws, size_t ws_size,
                              hipStream_t stream) {
  const float* guide    = (const float*)d_in[0];
  const float* target   = (const float*)d_in[1];
  const float* w_reduce = (const float*)d_in[2];
  const float* bn1g     = (const float*)d_in[3];
  const float* bn1b     = (const float*)d_in[4];
  const float* bn1m     = (const float*)d_in[5];
  const float* bn1v     = (const float*)d_in[6];
  const float* w_span   = (const float*)d_in[7];
  const float* b_span   = (const float*)d_in[8];
  const float* w_bconv  = (const float*)d_in[9];
  const float* bn3g     = (const float*)d_in[10];
  const float* bn3b     = (const float*)d_in[11];
  const float* bn3m     = (const float*)d_in[12];
  const float* bn3v     = (const float*)d_in[13];
  float* out = (float*)d_out;

  unsigned short* afrag     = (unsigned short*)d_ws;                      // 73728 B
  unsigned short* afrag_red = (unsigned short*)((char*)d_ws + 81920);     // 4096 B
  float* s3  = (float*)((char*)d_ws + 90112);
  float* sh3 = (float*)((char*)d_ws + 90368);
  unsigned short* inv = (unsigned short*)((char*)d_ws + (1 << 17));       // 16.8 MB

  hipLaunchKernelGGL(k0_prep, dim3(153), dim3(256), 0, stream,
                     w_bconv, w_reduce, bn3g, bn3b, bn3m, bn3v,
                     afrag, afrag_red, s3, sh3);
  hipLaunchKernelGGL(k1_fused, dim3(W_ / 16, H_ / 16, B_), dim3(512), 0, stream,
                     guide, target, afrag_red, bn1g, bn1b, bn1m, bn1v,
                     w_span, b_span, inv);
  hipLaunchKernelGGL(k2_conv, dim3(W_ / 32, H_ / 4, B_), dim3(256), 0, stream,
                     inv, afrag, s3, sh3, out);
}

// Round 9
// 166.025 us; speedup vs baseline: 1.1132x; 1.0084x over previous
//
#include <hip/hip_runtime.h>

#define B_  8
#define C_  64
#define H_  128
#define W_  128
#define HW_ (H_*W_)
#define NP_ ((size_t)B_*HW_)   // total pixels = 131072

typedef __attribute__((ext_vector_type(4)))  float f32x4;
typedef __attribute__((ext_vector_type(16))) float f32x16;
typedef __attribute__((ext_vector_type(8)))  short short8;

static __device__ __forceinline__ unsigned short f2bf(float f) {
  unsigned int u = __float_as_uint(f);
  u += 0x7fff + ((u >> 16) & 1);   // round-to-nearest-even
  return (unsigned short)(u >> 16);
}
static __device__ __forceinline__ float bf2f(unsigned short u) {
  return __uint_as_float((unsigned int)u << 16);
}

// ---------------- kernel 0: weight prep ----------------
__global__ void k0_prep(const float* __restrict__ w, const float* __restrict__ wred,
                        const float* __restrict__ g3, const float* __restrict__ b3,
                        const float* __restrict__ m3, const float* __restrict__ v3,
                        unsigned short* __restrict__ afrag,
                        unsigned short* __restrict__ afrag_red,
                        float* __restrict__ s3, float* __restrict__ sh3) {
  int idx = blockIdx.x * 256 + threadIdx.x;
  if (idx < 36864) {
    int j    = idx & 7;
    int lane = (idx >> 3) & 63;
    int fs   = idx >> 9;          // 0..71
    int ks16 = fs & 3;
    int kk   = (fs >> 2) % 9;
    int mh   = fs / 36;
    int oc = mh * 32 + (lane & 31);
    int ic = ks16 * 16 + (lane >> 5) * 8 + j;
    afrag[idx] = f2bf(w[(oc * 64 + ic) * 9 + kk]);
  } else if (idx < 38912) {
    int i2 = idx - 36864;         // 0..2047
    int j    = i2 & 7;
    int lane = (i2 >> 3) & 63;
    int ks   = i2 >> 9;           // 0..3
    int m  = lane & 31;
    int ic = ks * 16 + (lane >> 5) * 8 + j;
    afrag_red[i2] = (m < 16) ? f2bf(wred[m * 64 + ic]) : (unsigned short)0;
  } else if (idx < 38976) {
    int c = idx - 38912;
    float s = g3[c] * rsqrtf(v3[c] + 1e-5f);
    s3[c]  = s;
    sh3[c] = b3[c] - m3[c] * s;
  }
}

// ---------------- kernel 1: fused kernel-gen + involution ----------------
// 512 threads = 8 waves; 16x16 pixel tile; 2 lanes per pixel (h = lane>>5
// owns channel half / chunks 4h..4h+3 / kern group h). Kernel-gen via
// mfma_32x32x16 (w_reduce = A). Target tile (18x18 halo x 64ch) in LDS bf16
// [cell][chunk^(cell&7)].
// R9: MLP restructure — staging split into issue-all-loads (sv[6][8]) then
// convert+ds_write; guide channels preloaded to gv[32] BEFORE the barrier so
// guide traffic overlaps target staging. Math identical to R6/R8 k1.
__global__ __launch_bounds__(512, 4) void k1_fused(
    const float* __restrict__ guide, const float* __restrict__ target,
    const unsigned short* __restrict__ afrag_red,
    const float* __restrict__ bn1g, const float* __restrict__ bn1b,
    const float* __restrict__ bn1m, const float* __restrict__ bn1v,
    const float* __restrict__ w_span, const float* __restrict__ b_span,
    unsigned short* __restrict__ inv) {
  __shared__ __align__(16) unsigned short t16[324 * 64];   // 41472 B
  __shared__ f32x4 s_wspan[18][4];                         // [j][quad]
  __shared__ f32x4 s_s1v[4], s_sh1v[4];
  __shared__ float s_bsp[18];
  int t = threadIdx.x;
  if (t < 288) {
    int j = t >> 4, r = t & 15;
    ((float*)&s_wspan[j][0])[r] = w_span[t];     // w_span[j*16+r]
  }
  if (t < 16) {
    float s = bn1g[t] * rsqrtf(bn1v[t] + 1e-5f);
    ((float*)s_s1v)[t]  = s;
    ((float*)s_sh1v)[t] = bn1b[t] - bn1m[t] * s;
  }
  if (t < 18) s_bsp[t] = b_span[t];

  int b  = blockIdx.z;
  int h0 = blockIdx.y * 16, w0 = blockIdx.x * 16;
  const float* tb = target + (size_t)b * C_ * HW_;

  // ---- staging phase 1: issue all target loads (48 in flight) ----
  float sv[6][8];
  #pragma unroll
  for (int it = 0; it < 6; ++it) {
    int i = it * 512 + t;                  // 0..3071, valid < 2592
    int c8 = i / 324, cell = i - c8 * 324;
    int r = cell / 18, col = cell - r * 18;
    int hh = h0 + r - 1, ww = w0 + col - 1;
    bool iv = (i < 2592) && ((unsigned)hh < (unsigned)H_) && ((unsigned)ww < (unsigned)W_);
    const float* src = tb + (size_t)(c8 * 8) * HW_ + hh * W_ + ww;
    #pragma unroll
    for (int ci = 0; ci < 8; ++ci)
      sv[it][ci] = iv ? src[(size_t)ci * HW_] : 0.f;
  }

  // ---- guide preload: issue before barrier so it overlaps staging ----
  int wave = t >> 6, l = t & 63, h = l >> 5;
  int p   = wave * 32 + (l & 31);          // this lane's pixel (0..255)
  int tyP = p >> 4, txP = p & 15;
  const float* gpx = guide + (size_t)b * C_ * HW_ + (h0 + tyP) * W_ + (w0 + txP);
  float gv[32];
  #pragma unroll
  for (int ks = 0; ks < 4; ++ks) {
    int ch0 = ks * 16 + h * 8;
    #pragma unroll
    for (int j = 0; j < 8; ++j)
      gv[ks * 8 + j] = gpx[(size_t)(ch0 + j) * HW_];
  }

  short8 a_red[4];
  #pragma unroll
  for (int ks = 0; ks < 4; ++ks)
    a_red[ks] = *(const short8*)(afrag_red + ((size_t)(ks * 64 + l)) * 8);

  // ---- staging phase 2: convert + LDS write ----
  #pragma unroll
  for (int it = 0; it < 6; ++it) {
    int i = it * 512 + t;
    if (i < 2592) {
      int c8 = i / 324, cell = i - c8 * 324;
      short8 val;
      #pragma unroll
      for (int ci = 0; ci < 8; ++ci) val[ci] = (short)f2bf(sv[it][ci]);
      *(short8*)&t16[cell * 64 + ((c8 ^ (cell & 7)) * 8)] = val;
    }
  }
  __syncthreads();

  int cellC = (tyP + 1) * 18 + (txP + 1);

  // phase A: reduce conv via MFMA
  f32x16 xa;
  #pragma unroll
  for (int i = 0; i < 16; ++i) xa[i] = 0.f;
  #pragma unroll
  for (int ks = 0; ks < 4; ++ks) {
    short8 tvv = *(const short8*)&t16[cellC * 64 + (((2 * ks + h) ^ (cellC & 7)) * 8)];
    short8 bf;
    #pragma unroll
    for (int j = 0; j < 8; ++j)
      bf[j] = (short)f2bf(gv[ks * 8 + j] + bf2f((unsigned short)tvv[j]));
    xa = __builtin_amdgcn_mfma_f32_32x32x16_bf16(a_red[ks], bf, xa, 0, 0, 0);
  }
  // BN1 + ReLU
  f32x4 x0, x1;
  #pragma unroll
  for (int r = 0; r < 4; ++r) { x0[r] = xa[r]; x1[r] = xa[4 + r]; }
  {
    f32x4 sA = s_s1v[h], shA = s_sh1v[h], sB = s_s1v[2 + h], shB = s_sh1v[2 + h];
    #pragma unroll
    for (int r = 0; r < 4; ++r) {
      x0[r] = fmaxf(x0[r] * sA[r] + shA[r], 0.f);
      x1[r] = fmaxf(x1[r] * sB[r] + shB[r], 0.f);
    }
  }

  // phase B: span conv; partner-half exchange via shfl_xor(32)
  float kg[9];
  #pragma unroll
  for (int j9 = 0; j9 < 9; ++j9) {
    int jA = h * 9 + j9;
    int jB = (9 - 9 * h) + j9;
    f32x4 wA0 = s_wspan[jA][h], wA1 = s_wspan[jA][2 + h];
    f32x4 wB0 = s_wspan[jB][h], wB1 = s_wspan[jB][2 + h];
    float pa = 0.f, pb = 0.f;
    #pragma unroll
    for (int r = 0; r < 4; ++r) {
      pa += wA0[r] * x0[r] + wA1[r] * x1[r];
      pb += wB0[r] * x0[r] + wB1[r] * x1[r];
    }
    float recv = __shfl_xor(pb, 32, 64);
    kg[j9] = pa + recv + s_bsp[jA];
  }

  // phase C: involution for chunks c8 = 4h..4h+3
  size_t pix = ((size_t)b * H_ + (h0 + tyP)) * W_ + (w0 + txP);
  #pragma unroll
  for (int i = 0; i < 4; ++i) {
    int c8 = h * 4 + i;
    float a8[8];
    #pragma unroll
    for (int ci = 0; ci < 8; ++ci) a8[ci] = 0.f;
    #pragma unroll
    for (int di = 0; di < 3; ++di) {
      #pragma unroll
      for (int dj = 0; dj < 3; ++dj) {
        int cell = (tyP + di) * 18 + (txP + dj);
        short8 tv = *(const short8*)&t16[cell * 64 + ((c8 ^ (cell & 7)) * 8)];
        float k = kg[di * 3 + dj];
        #pragma unroll
        for (int ci = 0; ci < 8; ++ci) a8[ci] += k * bf2f((unsigned short)tv[ci]);
      }
    }
    short8 pv;
    #pragma unroll
    for (int ci = 0; ci < 8; ++ci) pv[ci] = (short)f2bf(a8[ci]);
    *(short8*)(inv + ((size_t)c8 * NP_ + pix) * 8) = pv;
  }
}

// ---------------- kernel 2: 3x3 conv, NO LDS — direct coalesced inv loads ---
__global__ __launch_bounds__(256, 4) void k2_conv(
    const unsigned short* __restrict__ inv, const unsigned short* __restrict__ afrag,
    const float* __restrict__ s3g, const float* __restrict__ sh3g,
    float* __restrict__ out) {
  int t = threadIdx.x;
  int wave = t >> 6, lane = t & 63;
  int mh = wave & 1;
  int rp = (wave >> 1) * 2;
  int b  = blockIdx.z;
  int h0 = blockIdx.y * 4;
  int w0 = blockIdx.x * 32;
  int tx = lane & 31, hb = lane >> 5;

  f32x16 acc0, acc1;
  #pragma unroll
  for (int i = 0; i < 16; ++i) { acc0[i] = 0.f; acc1[i] = 0.f; }

  const size_t bbase = (size_t)b * H_;
  const short8 z = {0, 0, 0, 0, 0, 0, 0, 0};

  #pragma unroll
  for (int kk = 0; kk < 9; ++kk) {
    const int di = kk / 3, dj = kk - di * 3;
    const unsigned short* ap = afrag + (((size_t)(mh * 9 + kk) * 4) * 64 + lane) * 8;
    int wj = w0 + tx + dj - 1;
    bool cok = (unsigned)wj < (unsigned)W_;
    int wc = min(max(wj, 0), W_ - 1);
    int hr0 = h0 + rp + di - 1;
    int hr1 = hr0 + 1;
    bool r0ok = cok && ((unsigned)hr0 < (unsigned)H_);
    bool r1ok = cok && ((unsigned)hr1 < (unsigned)H_);
    int hc0 = min(max(hr0, 0), H_ - 1);
    int hc1 = min(max(hr1, 0), H_ - 1);
    size_t p0 = (bbase + hc0) * W_ + wc;
    size_t p1 = (bbase + hc1) * W_ + wc;
    #pragma unroll
    for (int ks = 0; ks < 4; ++ks) {
      int c8 = ks * 2 + hb;
      short8 A  = *(const short8*)(ap + (size_t)ks * 512);
      short8 v0 = *(const short8*)(inv + ((size_t)c8 * NP_ + p0) * 8);
      short8 v1 = *(const short8*)(inv + ((size_t)c8 * NP_ + p1) * 8);
      short8 b0 = r0ok ? v0 : z;
      short8 b1 = r1ok ? v1 : z;
      acc0 = __builtin_amdgcn_mfma_f32_32x32x16_bf16(A, b0, acc0, 0, 0, 0);
      acc1 = __builtin_amdgcn_mfma_f32_32x32x16_bf16(A, b1, acc1, 0, 0, 0);
    }
  }

  // epilogue: BN3 + ReLU, NCHW f32
  int wcol = lane & 31;
  #pragma unroll
  for (int reg = 0; reg < 16; ++reg) {
    int oc = mh * 32 + (reg & 3) + 8 * (reg >> 2) + 4 * (lane >> 5);
    float s  = s3g[oc];
    float sh = sh3g[oc];
    float* op = out + ((size_t)b * C_ + oc) * HW_ + (h0 + rp) * W_ + w0 + wcol;
    op[0]  = fmaxf(acc0[reg] * s + sh, 0.f);
    op[W_] = fmaxf(acc1[reg] * s + sh, 0.f);
  }
}

extern "C" void kernel_launch(void* const* d_in, const int* in_sizes, int n_in,
                              void* d_out, int out_size, void* d_ws, size_t ws_size,
                              hipStream_t stream) {
  const float* guide    = (const float*)d_in[0];
  const float* target   = (const float*)d_in[1];
  const float* w_reduce = (const float*)d_in[2];
  const float* bn1g     = (const float*)d_in[3];
  const float* bn1b     = (const float*)d_in[4];
  const float* bn1m     = (const float*)d_in[5];
  const float* bn1v     = (const float*)d_in[6];
  const float* w_span   = (const float*)d_in[7];
  const float* b_span   = (const float*)d_in[8];
  const float* w_bconv  = (const float*)d_in[9];
  const float* bn3g     = (const float*)d_in[10];
  const float* bn3b     = (const float*)d_in[11];
  const float* bn3m     = (const float*)d_in[12];
  const float* bn3v     = (const float*)d_in[13];
  float* out = (float*)d_out;

  unsigned short* afrag     = (unsigned short*)d_ws;                      // 73728 B
  unsigned short* afrag_red = (unsigned short*)((char*)d_ws + 81920);     // 4096 B
  float* s3  = (float*)((char*)d_ws + 90112);
  float* sh3 = (float*)((char*)d_ws + 90368);
  unsigned short* inv = (unsigned short*)((char*)d_ws + (1 << 17));       // 16.8 MB

  hipLaunchKernelGGL(k0_prep, dim3(153), dim3(256), 0, stream,
                     w_bconv, w_reduce, bn3g, bn3b, bn3m, bn3v,
                     afrag, afrag_red, s3, sh3);
  hipLaunchKernelGGL(k1_fused, dim3(W_ / 16, H_ / 16, B_), dim3(512), 0, stream,
                     guide, target, afrag_red, bn1g, bn1b, bn1m, bn1v,
                     w_span, b_span, inv);
  hipLaunchKernelGGL(k2_conv, dim3(W_ / 32, H_ / 4, B_), dim3(256), 0, stream,
                     inv, afrag, s3, sh3, out);
}